// Round 10
// baseline (178.444 us; speedup 1.0000x reference)
//
#include <hip/hip_runtime.h>
#include <hip/hip_bf16.h>
#include <stdint.h>

// Problem: x[128,64,1024] fp32; W1,W2 [1024,1024] fp32 (torch Linear, y = x @ W^T)
//   h = x @ W1^T ; spikes = LIF_scan(h) ; out = spikes @ W2^T  (spike rate ~0.1-0.2%)
//
// GEMM1 via f16 2-split on MFMA: a = a0 + a1/4096 (+ r ~ 2^-22|a|),
//   A.B^T ~= A0B0 + (A0B1s + A1sB0)/4096
// Round 9 resubmit (r9 bench never ran - broker timeout): 3 dispatches (gap ~15us/dispatch
// measured r1/r3/r6/r8).
//   gemm_fused: BOTH A (x) and B (W1) split in the reg-staging path (r8-proven T14
//   issue-early/write-late; cvt rides the post-MFMA shadow) + W2T transpose rider blocks.
//   Then lif_scan, spike_matmul.
// ws: [0,1M) masks | [1,5M) W2T  (needs 5 MiB; else fp32 fallback path)

#define TT 128
#define BB 64
#define NN 1024
#define MROWS (TT * BB)          // 8192
#define SROW  (BB * NN)          // 65536
#define MiB   ((size_t)1048576)

typedef _Float16 h8  __attribute__((ext_vector_type(8)));
typedef float    f4  __attribute__((ext_vector_type(4)));
typedef float    v2f __attribute__((ext_vector_type(2)));

#if __has_builtin(__builtin_elementwise_fma)
#define V2FMA(a, b, c) __builtin_elementwise_fma((a), (b), (c))
#else
static __device__ __forceinline__ v2f v2fma_(v2f a, v2f b, v2f c) {
    v2f r; r[0] = fmaf(a[0], b[0], c[0]); r[1] = fmaf(a[1], b[1], c[1]); return r;
}
#define V2FMA(a, b, c) v2fma_((a), (b), (c))
#endif

// ---------------- MFMA GEMM + W2T riders -----------------------------------------------------
// blocks 0..511: 128x128 tile, 4 waves (2x2), 16x16x32 f16 MFMA, K_STEP=32, dbuf LDS.
//   A & B both reg-staged from fp32 (x, W1): loads issued at phase start, split-to-
//   (f16, f16*4096) + swizzled ds_write AFTER the MFMA cluster (off the critical path).
//   LDS [row][k] f16, 64B rows = 4x16B chunks, phys chunk = logical ^ ((row>>1)&3).
//   XCD remap: panel p=(ib>>6)*8+(ib&7), col cc=(ib>>3)&7.
// blocks 512..575: W2T transpose riders (16 32x32 tiles each; gemm HBM is idle anyway).
__global__ __launch_bounds__(256, 2) void gemm_fused(const float* __restrict__ X,
                                                     const float* __restrict__ W1,
                                                     const float* __restrict__ W2,
                                                     float* __restrict__ W2T,
                                                     float* __restrict__ C) {
    __shared__ _Float16 As0[2][4096], As1[2][4096];
    __shared__ _Float16 Bs0[2][4096], Bs1[2][4096];
    const int tid = threadIdx.x, lane = tid & 63, wid = tid >> 6;
    const int ib = blockIdx.x;

    if (ib >= 512) {   // ---- W2T transpose riders ----
        float* tile = (float*)&As0[0][0];          // 32x33 f32 fits easily
        const int tx = tid & 31, ty = tid >> 5;    // 32 x 8
#pragma unroll 1
        for (int it = 0; it < 16; ++it) {
            const int tIdx = (ib - 512) * 16 + it;
            const int bx = (tIdx & 31) * 32, by = (tIdx >> 5) * 32;
#pragma unroll
            for (int j = 0; j < 32; j += 8)
                tile[(ty + j) * 33 + tx] = W2[(size_t)(by + ty + j) * NN + bx + tx];
            __syncthreads();
#pragma unroll
            for (int j = 0; j < 32; j += 8)
                W2T[(size_t)(bx + ty + j) * NN + by + tx] = tile[tx * 33 + ty + j];
            __syncthreads();
        }
        return;
    }

    const int wr = wid >> 1, wc = wid & 1;
    const int p  = ((ib >> 6) << 3) + (ib & 7);
    const int cc = (ib >> 3) & 7;
    const int rowBase = p * 128, colBase = cc * 128;

    // staging geometry (shared by A and B): row sr = wid*32 + (lane>>2) (+16 second half),
    // f16-chunk sc = lane&3 covers k [8sc, 8sc+8) = 2 fp32 dwordx4 loads.
    const int sr = wid * 32 + (lane >> 2);
    const int sc = lane & 3;
    const int wsw = (sc ^ ((sr >> 1) & 3)) << 3;      // rows r,r+16 share (r>>1)&3 (bit4 only)
    const int wL0 = sr * 32 + wsw;                    // f16-elem LDS offsets
    const int wL1 = (sr + 16) * 32 + wsw;
    const size_t xOff = (size_t)(rowBase + sr) * NN + sc * 8;
    const size_t wOff = (size_t)(colBase + sr) * NN + sc * 8;

    // fragment read addrs: row, logical chunk = lane>>4, phys = logical ^ ((row>>1)&3)
    int fA[4], fB[4];
#pragma unroll
    for (int i = 0; i < 4; ++i) {
        const int ra = wr * 64 + i * 16 + (lane & 15);
        const int rb = wc * 64 + i * 16 + (lane & 15);
        fA[i] = ra * 32 + (((lane >> 4) ^ ((ra >> 1) & 3)) << 3);
        fB[i] = rb * 32 + (((lane >> 4) ^ ((rb >> 1) & 3)) << 3);
    }

    f4 acc0[4][4], acc1[4][4];
#pragma unroll
    for (int i = 0; i < 4; ++i)
#pragma unroll
        for (int j = 0; j < 4; ++j) { acc0[i][j] = (f4)0.0f; acc1[i][j] = (f4)0.0f; }

    f4 xa0, xa1, xb0, xb1;   // staged x  (rows sr, sr+16)
    f4 wa0, wa1, wb0, wb1;   // staged W1 (rows colBase+sr, +16)

#define LOADS(K0)                                              \
    do {                                                       \
        const size_t xo = xOff + (K0);                         \
        xa0 = *(const f4*)(X + xo);                            \
        xa1 = *(const f4*)(X + xo + 4);                        \
        xb0 = *(const f4*)(X + xo + (size_t)16 * NN);          \
        xb1 = *(const f4*)(X + xo + (size_t)16 * NN + 4);      \
        const size_t wo = wOff + (K0);                         \
        wa0 = *(const f4*)(W1 + wo);                           \
        wa1 = *(const f4*)(W1 + wo + 4);                       \
        wb0 = *(const f4*)(W1 + wo + (size_t)16 * NN);         \
        wb1 = *(const f4*)(W1 + wo + (size_t)16 * NN + 4);     \
    } while (0)

    // split (bitwise-identical to prep's formula) + swizzled write into buffer bi
#define CVTW(S0, S1, D0, D1, OFS)                                              \
    do {                                                                       \
        h8 hi, lo;                                                             \
        _Pragma("unroll") for (int e = 0; e < 4; ++e) {                        \
            const float f0 = (S0)[e], f1 = (S1)[e];                            \
            const _Float16 c0 = (_Float16)f0, c1 = (_Float16)f1;               \
            hi[e] = c0; hi[4 + e] = c1;                                        \
            lo[e]     = (_Float16)((f0 - (float)c0) * 4096.0f);                \
            lo[4 + e] = (_Float16)((f1 - (float)c1) * 4096.0f);                \
        }                                                                      \
        *(h8*)&(D0)[OFS] = hi; *(h8*)&(D1)[OFS] = lo;                          \
    } while (0)

#define WRITES(bi)                                   \
    do {                                             \
        CVTW(xa0, xa1, As0[bi], As1[bi], wL0);       \
        CVTW(xb0, xb1, As0[bi], As1[bi], wL1);       \
        CVTW(wa0, wa1, Bs0[bi], Bs1[bi], wL0);       \
        CVTW(wb0, wb1, Bs0[bi], Bs1[bi], wL1);       \
    } while (0)

    LOADS(0);
    WRITES(0);
    __syncthreads();

    for (int t = 0; t < 32; ++t) {
        const int cur = t & 1;
        if (t < 31) LOADS((t + 1) * 32);     // issue next-tile loads EARLY (under MFMA)
        h8 a0f[4], a1f[4], b0f[4], b1f[4];
#pragma unroll
        for (int i = 0; i < 4; ++i) {
            a0f[i] = *(const h8*)&As0[cur][fA[i]];
            a1f[i] = *(const h8*)&As1[cur][fA[i]];
            b0f[i] = *(const h8*)&Bs0[cur][fB[i]];
            b1f[i] = *(const h8*)&Bs1[cur][fB[i]];
        }
#pragma unroll
        for (int i = 0; i < 4; ++i)
#pragma unroll
            for (int j = 0; j < 4; ++j) {
                acc0[i][j] = __builtin_amdgcn_mfma_f32_16x16x32_f16(a0f[i], b0f[j], acc0[i][j], 0, 0, 0);
                acc1[i][j] = __builtin_amdgcn_mfma_f32_16x16x32_f16(a0f[i], b1f[j], acc1[i][j], 0, 0, 0);
                acc1[i][j] = __builtin_amdgcn_mfma_f32_16x16x32_f16(a1f[i], b0f[j], acc1[i][j], 0, 0, 0);
            }
        if (t < 31) WRITES(cur ^ 1);         // write-late: cvt rides the post-MFMA shadow
        __syncthreads();
    }
#undef LOADS
#undef CVTW
#undef WRITES

    // C/D layout (m89-verified): col = lane&15, row = (lane>>4)*4 + reg
    const int orow = rowBase + wr * 64 + (lane >> 4) * 4;
    const int ocol = colBase + wc * 64 + (lane & 15);
#pragma unroll
    for (int i = 0; i < 4; ++i)
#pragma unroll
        for (int j = 0; j < 4; ++j)
#pragma unroll
            for (int q = 0; q < 4; ++q)
                C[(size_t)(orow + i * 16 + q) * NN + ocol + j * 16] =
                    acc0[i][j][q] + acc1[i][j][q] * (1.0f / 4096.0f);
}

// ---------------- LIF scan: H[t,b,n] -> spike bitmasks (exact reference arithmetic) ---------
__global__ __launch_bounds__(256) void lif_scan(const float* __restrict__ H,
                                                unsigned long long* __restrict__ mask) {
    const int g = blockIdx.x * 256 + threadIdx.x;
    const int b = g >> 10;
    const int n = g & 1023;
    const int word = n >> 6;
    const bool lane0 = (threadIdx.x & 63) == 0;

    float v = 0.0f;
    float buf[16];
#pragma unroll
    for (int j = 0; j < 16; ++j) buf[j] = H[(size_t)j * SROW + g];

    for (int t0 = 0; t0 < TT; t0 += 16) {
        float nbuf[16];
        if (t0 + 16 < TT) {
#pragma unroll
            for (int j = 0; j < 16; ++j) nbuf[j] = H[(size_t)(t0 + 16 + j) * SROW + g];
        } else {
#pragma unroll
            for (int j = 0; j < 16; ++j) nbuf[j] = 0.f;
        }
#pragma unroll
        for (int j = 0; j < 16; ++j) {
            const float x = buf[j];
            const float h = v + (x - v) * 0.5f;
            const bool s = (h >= 1.0f);
            v = s ? 0.0f : h;
            const unsigned long long m = __ballot(s);
            if (lane0) mask[((size_t)(t0 + j) * BB + b) * 16 + word] = m;
        }
#pragma unroll
        for (int j = 0; j < 16; ++j) buf[j] = nbuf[j];
    }
}

// ---------------- sparse GEMM2: out[r,:] = sum_{n: spike} W2T[n,:] ---------------------------
__global__ __launch_bounds__(256) void spike_matmul(const unsigned long long* __restrict__ mask,
                                                    const float* __restrict__ W2T,
                                                    float* __restrict__ out) {
    __shared__ unsigned long long sw[16];
    const int r = blockIdx.x;
    const int tid = threadIdx.x;
    if (tid < 16) sw[tid] = mask[(size_t)r * 16 + tid];
    __syncthreads();

    f4 acc = (f4)0.0f;
#pragma unroll 1
    for (int w = 0; w < 16; ++w) {
        unsigned long long bits = sw[w];
        while (bits) {
            const int n = w * 64 + (__ffsll(bits) - 1);
            bits &= bits - 1;
            const f4 rv = reinterpret_cast<const f4*>(W2T + (size_t)n * NN)[tid];
            acc[0] += rv[0]; acc[1] += rv[1]; acc[2] += rv[2]; acc[3] += rv[3];
        }
    }
    reinterpret_cast<f4*>(out + (size_t)r * NN)[tid] = acc;
}

// ---------------- W2 transpose (fallback path only) -----------------------------------------
__global__ __launch_bounds__(256) void transpose_nn(const float* __restrict__ in,
                                                    float* __restrict__ out) {
    __shared__ float tile[32][33];
    const int bx = blockIdx.x * 32, by = blockIdx.y * 32;
    const int tx = threadIdx.x, ty = threadIdx.y;
#pragma unroll
    for (int j = 0; j < 32; j += 8)
        tile[ty + j][tx] = in[(size_t)(by + ty + j) * NN + bx + tx];
    __syncthreads();
#pragma unroll
    for (int j = 0; j < 32; j += 8)
        out[(size_t)(bx + ty + j) * NN + by + tx] = tile[tx][ty + j];
}

// ---------------- fallback fp32 GEMM (used only if ws too small) -----------------------------
#define BM 128
#define BN 64
#define BK 16
__global__ __launch_bounds__(256, 4) void gemm1_f32(const float* __restrict__ A,
                                                    const float* __restrict__ B,
                                                    float* __restrict__ C) {
    __shared__ float Asb[2][BK][132];
    __shared__ float Bsb[2][BK][68];
    const int tid = threadIdx.x;
    const int ty = tid >> 4;
    const int tx = tid & 15;
    const int rowBase = blockIdx.y * BM;
    const int colBase = blockIdx.x * BN;
    const int sr = tid >> 2;
    const int sk = (tid & 3) * 4;

    const float* Ap0 = A + (size_t)(rowBase + sr) * NN + sk;
    const float* Ap1 = Ap0 + (size_t)64 * NN;
    const float* Bp  = B + (size_t)(colBase + sr) * NN + sk;

    v2f acc[4][4];
#pragma unroll
    for (int i = 0; i < 4; ++i)
#pragma unroll
        for (int j = 0; j < 4; ++j) acc[i][j] = (v2f){0.f, 0.f};

    float4 ra0 = *(const float4*)Ap0;
    float4 ra1 = *(const float4*)Ap1;
    float4 rb  = *(const float4*)Bp;

#define STW(buf)                                                                       \
    do {                                                                               \
        Asb[buf][sk + 0][sr] = ra0.x; Asb[buf][sk + 1][sr] = ra0.y;                    \
        Asb[buf][sk + 2][sr] = ra0.z; Asb[buf][sk + 3][sr] = ra0.w;                    \
        Asb[buf][sk + 0][sr + 64] = ra1.x; Asb[buf][sk + 1][sr + 64] = ra1.y;          \
        Asb[buf][sk + 2][sr + 64] = ra1.z; Asb[buf][sk + 3][sr + 64] = ra1.w;          \
        Bsb[buf][sk + 0][sr] = rb.x;  Bsb[buf][sk + 1][sr] = rb.y;                     \
        Bsb[buf][sk + 2][sr] = rb.z;  Bsb[buf][sk + 3][sr] = rb.w;                     \
    } while (0)

    STW(0);
    __syncthreads();
    const int NT = NN / BK;
    for (int t = 0; t < NT; ++t) {
        const int cur = t & 1;
        if (t < NT - 1) {
            const int ko = (t + 1) * BK;
            ra0 = *(const float4*)(Ap0 + ko);
            ra1 = *(const float4*)(Ap1 + ko);
            rb  = *(const float4*)(Bp + ko);
        }
#pragma unroll
        for (int k = 0; k < BK; ++k) {
            const v2f* ap = (const v2f*)&Asb[cur][k][ty * 8];
            const float4 bf = *(const float4*)&Bsb[cur][k][tx * 4];
            const float bb[4] = {bf.x, bf.y, bf.z, bf.w};
            const v2f a0 = ap[0], a1 = ap[1], a2 = ap[2], a3 = ap[3];
#pragma unroll
            for (int j = 0; j < 4; ++j) {
                const v2f bd = {bb[j], bb[j]};
                acc[0][j] = V2FMA(a0, bd, acc[0][j]);
                acc[1][j] = V2FMA(a1, bd, acc[1][j]);
                acc[2][j] = V2FMA(a2, bd, acc[2][j]);
                acc[3][j] = V2FMA(a3, bd, acc[3][j]);
            }
        }
        if (t < NT - 1) STW(cur ^ 1);
        __syncthreads();
    }
#undef STW
    float* Cp = C + (size_t)(rowBase + ty * 8) * NN + colBase + tx * 4;
#pragma unroll
    for (int rp = 0; rp < 4; ++rp) {
        float4 lo = {acc[rp][0][0], acc[rp][1][0], acc[rp][2][0], acc[rp][3][0]};
        float4 hi = {acc[rp][0][1], acc[rp][1][1], acc[rp][2][1], acc[rp][3][1]};
        *(float4*)(Cp + (size_t)(2 * rp) * NN)     = lo;
        *(float4*)(Cp + (size_t)(2 * rp + 1) * NN) = hi;
    }
}

extern "C" void kernel_launch(void* const* d_in, const int* in_sizes, int n_in,
                              void* d_out, int out_size, void* d_ws, size_t ws_size,
                              hipStream_t stream) {
    const float* x  = (const float*)d_in[0];
    const float* W1 = (const float*)d_in[1];
    const float* W2 = (const float*)d_in[2];
    float* out = (float*)d_out;

    unsigned long long* mask = (unsigned long long*)d_ws;
    float* W2T = (float*)((char*)d_ws + 1 * MiB);

    if (ws_size >= 5 * MiB) {
        gemm_fused<<<576, 256, 0, stream>>>(x, W1, W2, W2T, out);
    } else {
        transpose_nn<<<dim3(32, 32), dim3(32, 8), 0, stream>>>(W2, W2T);
        gemm1_f32<<<dim3(NN / BN, MROWS / BM), 256, 0, stream>>>(x, W1, out);
    }
    lif_scan<<<SROW / 256, 256, 0, stream>>>(out, mask);
    spike_matmul<<<MROWS, 256, 0, stream>>>(mask, W2T, out);
}